// Round 1
// baseline (368.410 us; speedup 1.0000x reference)
//
#include <hip/hip_runtime.h>
#include <hip/hip_fp16.h>

#define N_NODES 100000
#define N_EDGES 1600000
#define NBUCKET 196          // ceil(100000 / 512)
#define CAP     8960         // per-bucket capacity: mean 8163, sigma 90 -> +8.8 sigma
#define EPB     6250         // edges per block in partition (256 blocks)

typedef _Float16 half8 __attribute__((ext_vector_type(8)));
typedef float float4v __attribute__((ext_vector_type(4)));

// acc += (float)lo_half(w)  /  acc += (float)hi_half(w)  in ONE VALU op each.
// v_fma_mix_f32: numerically identical to cvt+add (h exact in f32, x1.0 exact).
__device__ __forceinline__ void fmix_lo(float& a, unsigned int w, float one) {
    asm("v_fma_mix_f32 %0, %1, %2, %0 op_sel:[0,0,0] op_sel_hi:[1,0,0]"
        : "+v"(a) : "v"(w), "v"(one));
}
__device__ __forceinline__ void fmix_hi(float& a, unsigned int w, float one) {
    asm("v_fma_mix_f32 %0, %1, %2, %0 op_sel:[1,0,0] op_sel_hi:[1,0,0]"
        : "+v"(a) : "v"(w), "v"(one));
}

// ---------------- partition edges into fixed-capacity bucket segments
// packed entry: (src << 9) | (dst & 511)  [src < 2^17, bucket-local dst < 2^9]
// Blocks 256..275 instead perform the W->fp16 B-fragment swizzles (fused k_wswz).
__launch_bounds__(256)
__global__ void k_part_wswz(const int* __restrict__ src, const int* __restrict__ dst,
                            int* __restrict__ bcur, int* __restrict__ ebuf, int E,
                            const float* __restrict__ W1, const float* __restrict__ W2,
                            const float* __restrict__ W3, _Float16* __restrict__ wz1,
                            _Float16* __restrict__ wz2, _Float16* __restrict__ wz3) {
    if (blockIdx.x >= 256) {
        // -------- weight swizzle path (20 blocks * 256 = 5120 threads)
        int t = (blockIdx.x - 256) * 256 + threadIdx.x;
        const float* W; _Float16* wsz; int BN;
        if (t < 2048)      { W = W1; wsz = wz1; BN = 128; }
        else if (t < 4096) { W = W2; wsz = wz2; BN = 128; t -= 2048; }
        else if (t < 5120) { W = W3; wsz = wz3; BN = 64;  t -= 4096; }
        else return;
        const int l = t & 63;
        const int kblk = (t >> 6) & 3;
        const int nt = t >> 8;
        const int krow = kblk * 32 + ((l >> 4) << 3);
        const int col = nt * 16 + (l & 15);
        _Float16 v[8];
#pragma unroll
        for (int j = 0; j < 8; ++j) v[j] = (_Float16)W[(krow + j) * BN + col];
        *(uint4*)&wsz[t << 3] = *(uint4*)v;
        return;
    }
    __shared__ int hist[200];
    __shared__ int basebkt[200];
    const int tid = threadIdx.x;
    if (tid < 200) hist[tid] = 0;
    __syncthreads();
    const int e0 = blockIdx.x * EPB, e1 = min(e0 + EPB, E);
    for (int e = e0 + tid; e < e1; e += 256) atomicAdd(&hist[dst[e] >> 9], 1);
    __syncthreads();
    if (tid < NBUCKET) {
        int h = hist[tid];
        basebkt[tid] = tid * CAP + (h ? atomicAdd(&bcur[tid], h) : 0);
    }
    __syncthreads();
    if (tid < 200) hist[tid] = 0;
    __syncthreads();
    for (int e = e0 + tid; e < e1; e += 256) {
        int d = dst[e];
        int bk = d >> 9;
        int o = atomicAdd(&hist[bk], 1);
        ebuf[basebkt[bk] + o] = (src[e] << 9) | (d & 511);
    }
}

// ---------------- per-bucket counting sort -> deg, stv, dinv, adj (bucketed layout)
__launch_bounds__(256)
__global__ void k_bsort(const int* __restrict__ ebuf, const int* __restrict__ bcur,
                        int* __restrict__ adj, int* __restrict__ stv,
                        int* __restrict__ deg, float* __restrict__ dinv, int N) {
    __shared__ int cnt[512];
    __shared__ int offs[512];
    const int b = blockIdx.x;
    const int tid = threadIdx.x;
    const int base = b * CAP;
    const int n_b = min(bcur[b], CAP);
    const int node0 = b << 9;
    cnt[tid] = 0; cnt[tid + 256] = 0;
    __syncthreads();
    for (int i = tid; i < n_b; i += 256)
        atomicAdd(&cnt[ebuf[base + i] & 511], 1);
    __syncthreads();
    if (tid < 64) {  // wave-0 exclusive scan of 512
        int v[8], tot = 0;
#pragma unroll
        for (int j = 0; j < 8; ++j) { int t = cnt[tid * 8 + j]; v[j] = tot; tot += t; }
        int inc = tot;
#pragma unroll
        for (int d = 1; d < 64; d <<= 1) {
            int u = __shfl_up(inc, d, 64);
            if (tid >= d) inc += u;
        }
        const int excl = inc - tot;
#pragma unroll
        for (int j = 0; j < 8; ++j) offs[tid * 8 + j] = excl + v[j];
    }
    __syncthreads();
#pragma unroll
    for (int h = 0; h < 2; ++h) {
        int local = tid + h * 256;
        int node = node0 + local;
        if (node < N) {
            stv[node] = base + offs[local];
            deg[node] = cnt[local];
            dinv[node] = rsqrtf((float)(cnt[local] + 1));
        }
    }
    __syncthreads();
    for (int i = tid; i < n_b; i += 256) {  // offs doubles as cursor
        int pk = ebuf[base + i];
        int pos = atomicAdd(&offs[pk & 511], 1);
        adj[base + pos] = pk >> 9;
    }
}

// ---------------- MFMA GEMM: tp[i][:] = fp16( dinv[i] * (X[i][:] @ W) ), K=128
template <int BN, bool AFP16>
__launch_bounds__(256, 4)
__global__ void k_gemm_mfma(const void* __restrict__ Xv, const _Float16* __restrict__ wsz,
                            const float* __restrict__ dinv, __half* __restrict__ out, int N) {
    constexpr int NT = BN / 16;
    constexpr int PAD = 8;
    __shared__ __align__(16) _Float16 smem[BN * 128];  // B frags; reused for epilogue

    const int tid = threadIdx.x;
    for (int i = tid; i < BN * 16; i += 256)
        *(uint4*)&smem[i << 3] = *(const uint4*)&wsz[i << 3];

    const int w = tid >> 6;
    const int lane = tid & 63;
    const int q = lane >> 4;
    const int m = lane & 15;
    const int row0 = blockIdx.x * 64;
    const int arow = row0 + w * 16 + m;
    const int arowc = arow < N ? arow : N - 1;

    float4v acc[NT];
#pragma unroll
    for (int nt = 0; nt < NT; ++nt) acc[nt] = (float4v){0.f, 0.f, 0.f, 0.f};

    __syncthreads();

#pragma unroll
    for (int kblk = 0; kblk < 4; ++kblk) {
        half8 af;
        if constexpr (AFP16) {
            const _Float16* A = (const _Float16*)Xv + (size_t)arowc * 128 + (q << 3);
            af = *(const half8*)(A + kblk * 32);
        } else {
            const float* A = (const float*)Xv + (size_t)arowc * 128 + (q << 3);
            float4 a0 = *(const float4*)(A + kblk * 32);
            float4 a1 = *(const float4*)(A + kblk * 32 + 4);
            af[0] = (_Float16)a0.x; af[1] = (_Float16)a0.y;
            af[2] = (_Float16)a0.z; af[3] = (_Float16)a0.w;
            af[4] = (_Float16)a1.x; af[5] = (_Float16)a1.y;
            af[6] = (_Float16)a1.z; af[7] = (_Float16)a1.w;
        }
#pragma unroll
        for (int nt = 0; nt < NT; ++nt) {
            half8 bf = *(const half8*)&smem[(((nt << 2) + kblk) << 9) + (lane << 3)];
            acc[nt] = __builtin_amdgcn_mfma_f32_16x16x32_f16(af, bf, acc[nt], 0, 0, 0);
        }
    }

    float s[4];
#pragma unroll
    for (int r = 0; r < 4; ++r) {
        int rr = row0 + w * 16 + q * 4 + r;
        s[r] = dinv[rr < N ? rr : N - 1];
    }
    __syncthreads();  // all B reads done before smem reuse
    _Float16* eb = smem;
#pragma unroll
    for (int nt = 0; nt < NT; ++nt)
#pragma unroll
        for (int r = 0; r < 4; ++r)
            eb[(w * 16 + q * 4 + r) * (BN + PAD) + nt * 16 + m] = (_Float16)(acc[nt][r] * s[r]);
    __syncthreads();
    constexpr int CPR = BN / 8;
    for (int i = tid; i < 64 * CPR; i += 256) {
        int row = i / CPR;
        int cf = (i % CPR) * 8;
        if (row0 + row < N)
            *(uint4*)&out[(size_t)(row0 + row) * BN + cf] = *(uint4*)&eb[row * (BN + PAD) + cf];
    }
}

// ---------------- d=128 aggregation: 4 edges per wave-load
// 4 groups of 16 lanes; group g handles edge e+g; each lane loads uint4 (8 cols).
template <bool RELU>
__launch_bounds__(256)
__global__ void k_agg128(const __half* __restrict__ tp, const int* __restrict__ adj,
                         const int* __restrict__ startv, const int* __restrict__ deg,
                         const float* __restrict__ dinv, const float* __restrict__ bias,
                         _Float16* __restrict__ out, int N) {
    const int node = (blockIdx.x << 2) + (threadIdx.x >> 6);
    const int lane = threadIdx.x & 63;
    if (node >= N) return;
    const int s = startv[node];
    const int cnt = deg[node];
    const float di = dinv[node];
    const float one = 1.0f;
    const int g = lane >> 4;        // edge group 0..3
    const int sl = lane & 15;       // 16 B chunk within row
    const uint4* rowb = (const uint4*)tp;   // row stride = 16 uint4 (256 B)

    float acc[8] = {0.f, 0.f, 0.f, 0.f, 0.f, 0.f, 0.f, 0.f};
    auto addrow = [&](uint4 v) {
        fmix_lo(acc[0], v.x, one); fmix_hi(acc[1], v.x, one);
        fmix_lo(acc[2], v.y, one); fmix_hi(acc[3], v.y, one);
        fmix_lo(acc[4], v.z, one); fmix_hi(acc[5], v.z, one);
        fmix_lo(acc[6], v.w, one); fmix_hi(acc[7], v.w, one);
    };
    if (g == 0) addrow(rowb[(size_t)node * 16 + sl]);   // self-loop once

    int e = 0;
    for (; e + 16 <= cnt; e += 16) {
        int j[4];
#pragma unroll
        for (int u = 0; u < 4; ++u) j[u] = __builtin_nontemporal_load(&adj[s + e + 4 * u + g]);
        uint4 v[4];
#pragma unroll
        for (int u = 0; u < 4; ++u) v[u] = rowb[(size_t)j[u] * 16 + sl];
#pragma unroll
        for (int u = 0; u < 4; ++u) addrow(v[u]);
    }
    if (e + 8 <= cnt) {
        int j[2];
#pragma unroll
        for (int u = 0; u < 2; ++u) j[u] = __builtin_nontemporal_load(&adj[s + e + 4 * u + g]);
        uint4 v[2];
#pragma unroll
        for (int u = 0; u < 2; ++u) v[u] = rowb[(size_t)j[u] * 16 + sl];
#pragma unroll
        for (int u = 0; u < 2; ++u) addrow(v[u]);
        e += 8;
    }
    if (e + 4 <= cnt) {
        addrow(rowb[(size_t)__builtin_nontemporal_load(&adj[s + e + g]) * 16 + sl]);
        e += 4;
    }
    if (e + g < cnt)
        addrow(rowb[(size_t)__builtin_nontemporal_load(&adj[s + e + g]) * 16 + sl]);

#pragma unroll
    for (int i = 0; i < 8; ++i) {
        acc[i] += __shfl_xor(acc[i], 32);
        acc[i] += __shfl_xor(acc[i], 16);
    }
    if (g == 0) {
        float4 b0 = *(const float4*)&bias[sl * 8];
        float4 b1 = *(const float4*)&bias[sl * 8 + 4];
        float o[8];
        o[0] = di * acc[0] + b0.x; o[1] = di * acc[1] + b0.y;
        o[2] = di * acc[2] + b0.z; o[3] = di * acc[3] + b0.w;
        o[4] = di * acc[4] + b1.x; o[5] = di * acc[5] + b1.y;
        o[6] = di * acc[6] + b1.z; o[7] = di * acc[7] + b1.w;
        if (RELU)
#pragma unroll
            for (int i = 0; i < 8; ++i) o[i] = fmaxf(o[i], 0.f);
        __half2 ov[4];
#pragma unroll
        for (int i = 0; i < 4; ++i) ov[i] = __floats2half2_rn(o[2 * i], o[2 * i + 1]);
        *(uint4*)&out[(size_t)node * 128 + sl * 8] = *(uint4*)ov;
    }
}

// ---------------- d=64 aggregation (fp32 out): 4 edges per wave-load
__launch_bounds__(256)
__global__ void k_agg64(const __half* __restrict__ tp, const int* __restrict__ adj,
                        const int* __restrict__ startv, const int* __restrict__ deg,
                        const float* __restrict__ dinv, const float* __restrict__ bias,
                        float* __restrict__ out, int N) {
    const int node = (blockIdx.x << 2) + (threadIdx.x >> 6);
    const int lane = threadIdx.x & 63;
    if (node >= N) return;
    const int s = startv[node];
    const int cnt = deg[node];
    const float di = dinv[node];
    const float one = 1.0f;
    const int g = lane >> 4;
    const int sl = lane & 15;
    const uint2* rowb = (const uint2*)tp;   // row stride = 16 uint2 (128 B)

    float acc[4] = {0.f, 0.f, 0.f, 0.f};
    auto addrow = [&](uint2 v) {
        fmix_lo(acc[0], v.x, one); fmix_hi(acc[1], v.x, one);
        fmix_lo(acc[2], v.y, one); fmix_hi(acc[3], v.y, one);
    };
    if (g == 0) addrow(rowb[(size_t)node * 16 + sl]);   // self-loop

    int e = 0;
    for (; e + 16 <= cnt; e += 16) {
        int j[4];
#pragma unroll
        for (int u = 0; u < 4; ++u) j[u] = __builtin_nontemporal_load(&adj[s + e + 4 * u + g]);
        uint2 v[4];
#pragma unroll
        for (int u = 0; u < 4; ++u) v[u] = rowb[(size_t)j[u] * 16 + sl];
#pragma unroll
        for (int u = 0; u < 4; ++u) addrow(v[u]);
    }
    if (e + 8 <= cnt) {
        int j[2];
#pragma unroll
        for (int u = 0; u < 2; ++u) j[u] = __builtin_nontemporal_load(&adj[s + e + 4 * u + g]);
        uint2 v[2];
#pragma unroll
        for (int u = 0; u < 2; ++u) v[u] = rowb[(size_t)j[u] * 16 + sl];
#pragma unroll
        for (int u = 0; u < 2; ++u) addrow(v[u]);
        e += 8;
    }
    if (e + 4 <= cnt) {
        addrow(rowb[(size_t)__builtin_nontemporal_load(&adj[s + e + g]) * 16 + sl]);
        e += 4;
    }
    if (e + g < cnt)
        addrow(rowb[(size_t)__builtin_nontemporal_load(&adj[s + e + g]) * 16 + sl]);

#pragma unroll
    for (int i = 0; i < 4; ++i) {
        acc[i] += __shfl_xor(acc[i], 32);
        acc[i] += __shfl_xor(acc[i], 16);
    }
    if (g == 0) {
        float4 bb = *(const float4*)&bias[sl * 4];
        float4 o;
        o.x = di * acc[0] + bb.x; o.y = di * acc[1] + bb.y;
        o.z = di * acc[2] + bb.z; o.w = di * acc[3] + bb.w;
        *(float4*)&out[(size_t)node * 64 + sl * 4] = o;
    }
}

extern "C" void kernel_launch(void* const* d_in, const int* in_sizes, int n_in,
                              void* d_out, int out_size, void* d_ws, size_t ws_size,
                              hipStream_t stream) {
    const float* x  = (const float*)d_in[0];
    const int*   ei = (const int*)d_in[1];
    const float* W1 = (const float*)d_in[2];
    const float* b1 = (const float*)d_in[3];
    const float* W2 = (const float*)d_in[4];
    const float* b2 = (const float*)d_in[5];
    const float* W3 = (const float*)d_in[6];
    const float* b3 = (const float*)d_in[7];
    float* out = (float*)d_out;
    const int* src = ei;            // edge_index[0]
    const int* dst = ei + N_EDGES;  // edge_index[1]

    char* p = (char*)d_ws;
    __half* tp      = (__half*)p;    p += (size_t)N_NODES * 128 * 2;   // 25.6 MB
    _Float16* hbuf  = (_Float16*)p;  p += (size_t)N_NODES * 128 * 2;   // 25.6 MB
    int*   deg  = (int*)p;    p += (size_t)N_NODES * 4;
    float* dinv = (float*)p;  p += (size_t)N_NODES * 4;
    int*   stv  = (int*)p;    p += (size_t)N_NODES * 4;
    int*   bCur = (int*)p;    p += 1024;                               // bucket fill counts
    int*   adj  = (int*)p;    p += (size_t)NBUCKET * CAP * 4 + 16384;  // 7.0 MB bucketed
    _Float16* wz1 = (_Float16*)p; p += 16384 * 2;                      // 32 KB
    _Float16* wz2 = (_Float16*)p; p += 16384 * 2;                      // 32 KB
    _Float16* wz3 = (_Float16*)p; p += 8192 * 2;                       // 16 KB
    size_t need = (size_t)(p - (char*)d_ws);
    if (ws_size < need) return;  // visible failure rather than OOB

    int* ebuf = (int*)tp;  // 7.0 MB alias; tp not live until layer-1 GEMM

    hipMemsetAsync(bCur, 0, 1024, stream);
    k_part_wswz<<<276, 256, 0, stream>>>(src, dst, bCur, ebuf, N_EDGES,
                                         W1, W2, W3, wz1, wz2, wz3);
    k_bsort<<<NBUCKET, 256, 0, stream>>>(ebuf, bCur, adj, stv, deg, dinv, N_NODES);

    const int gb = (N_NODES + 63) / 64;
    const int ab = (N_NODES + 3) / 4;
    // layer 1: relu(agg(x@W1) + b1) -> fp16 hbuf
    k_gemm_mfma<128, false><<<gb, 256, 0, stream>>>(x, wz1, dinv, tp, N_NODES);
    k_agg128<true><<<ab, 256, 0, stream>>>(tp, adj, stv, deg, dinv, b1, hbuf, N_NODES);
    // layer 2
    k_gemm_mfma<128, true><<<gb, 256, 0, stream>>>(hbuf, wz2, dinv, tp, N_NODES);
    k_agg128<true><<<ab, 256, 0, stream>>>(tp, adj, stv, deg, dinv, b2, hbuf, N_NODES);
    // layer 3: agg(h@W3) + b3 (no relu) -> fp32 out
    k_gemm_mfma<64, true><<<gb, 256, 0, stream>>>(hbuf, wz3, dinv, tp, N_NODES);
    k_agg64<<<ab, 256, 0, stream>>>(tp, adj, stv, deg, dinv, b3, out, N_NODES);
}

// Round 2
// 355.409 us; speedup vs baseline: 1.0366x; 1.0366x over previous
//
#include <hip/hip_runtime.h>
#include <hip/hip_fp16.h>

#define N_NODES 100000
#define N_EDGES 1600000
#define NBUCKET 196          // ceil(100000 / 512)
#define CAP     8960         // per-bucket capacity: mean 8163, sigma 90 -> +8.8 sigma
#define EPB     6250         // edges per block in partition (256 blocks)

typedef _Float16 half8 __attribute__((ext_vector_type(8)));
typedef float float4v __attribute__((ext_vector_type(4)));

// acc += (float)lo_half(w)  /  acc += (float)hi_half(w)  in ONE VALU op each.
// v_fma_mix_f32: numerically identical to cvt+add (h exact in f32, x1.0 exact).
__device__ __forceinline__ void fmix_lo(float& a, unsigned int w, float one) {
    asm("v_fma_mix_f32 %0, %1, %2, %0 op_sel:[0,0,0] op_sel_hi:[1,0,0]"
        : "+v"(a) : "v"(w), "v"(one));
}
__device__ __forceinline__ void fmix_hi(float& a, unsigned int w, float one) {
    asm("v_fma_mix_f32 %0, %1, %2, %0 op_sel:[1,0,0] op_sel_hi:[1,0,0]"
        : "+v"(a) : "v"(w), "v"(one));
}

// ---------------- partition edges into fixed-capacity bucket segments
// packed entry: (src << 9) | (dst & 511)  [src < 2^17, bucket-local dst < 2^9]
// Blocks 256..275 instead perform the W->fp16 B-fragment swizzles (fused k_wswz).
__launch_bounds__(256)
__global__ void k_part_wswz(const int* __restrict__ src, const int* __restrict__ dst,
                            int* __restrict__ bcur, int* __restrict__ ebuf, int E,
                            const float* __restrict__ W1, const float* __restrict__ W2,
                            const float* __restrict__ W3, _Float16* __restrict__ wz1,
                            _Float16* __restrict__ wz2, _Float16* __restrict__ wz3) {
    if (blockIdx.x >= 256) {
        // -------- weight swizzle path (20 blocks * 256 = 5120 threads)
        int t = (blockIdx.x - 256) * 256 + threadIdx.x;
        const float* W; _Float16* wsz; int BN;
        if (t < 2048)      { W = W1; wsz = wz1; BN = 128; }
        else if (t < 4096) { W = W2; wsz = wz2; BN = 128; t -= 2048; }
        else if (t < 5120) { W = W3; wsz = wz3; BN = 64;  t -= 4096; }
        else return;
        const int l = t & 63;
        const int kblk = (t >> 6) & 3;
        const int nt = t >> 8;
        const int krow = kblk * 32 + ((l >> 4) << 3);
        const int col = nt * 16 + (l & 15);
        _Float16 v[8];
#pragma unroll
        for (int j = 0; j < 8; ++j) v[j] = (_Float16)W[(krow + j) * BN + col];
        *(uint4*)&wsz[t << 3] = *(uint4*)v;
        return;
    }
    __shared__ int hist[200];
    __shared__ int basebkt[200];
    const int tid = threadIdx.x;
    if (tid < 200) hist[tid] = 0;
    __syncthreads();
    const int e0 = blockIdx.x * EPB, e1 = min(e0 + EPB, E);
    for (int e = e0 + tid; e < e1; e += 256) atomicAdd(&hist[dst[e] >> 9], 1);
    __syncthreads();
    if (tid < NBUCKET) {
        int h = hist[tid];
        basebkt[tid] = tid * CAP + (h ? atomicAdd(&bcur[tid], h) : 0);
    }
    __syncthreads();
    if (tid < 200) hist[tid] = 0;
    __syncthreads();
    for (int e = e0 + tid; e < e1; e += 256) {
        int d = dst[e];
        int bk = d >> 9;
        int o = atomicAdd(&hist[bk], 1);
        ebuf[basebkt[bk] + o] = (src[e] << 9) | (d & 511);
    }
}

// ---------------- per-bucket counting sort -> deg, stv, dinv, adj (bucketed layout)
__launch_bounds__(256)
__global__ void k_bsort(const int* __restrict__ ebuf, const int* __restrict__ bcur,
                        int* __restrict__ adj, int* __restrict__ stv,
                        int* __restrict__ deg, float* __restrict__ dinv, int N) {
    __shared__ int cnt[512];
    __shared__ int offs[512];
    const int b = blockIdx.x;
    const int tid = threadIdx.x;
    const int base = b * CAP;
    const int n_b = min(bcur[b], CAP);
    const int node0 = b << 9;
    cnt[tid] = 0; cnt[tid + 256] = 0;
    __syncthreads();
    for (int i = tid; i < n_b; i += 256)
        atomicAdd(&cnt[ebuf[base + i] & 511], 1);
    __syncthreads();
    if (tid < 64) {  // wave-0 exclusive scan of 512
        int v[8], tot = 0;
#pragma unroll
        for (int j = 0; j < 8; ++j) { int t = cnt[tid * 8 + j]; v[j] = tot; tot += t; }
        int inc = tot;
#pragma unroll
        for (int d = 1; d < 64; d <<= 1) {
            int u = __shfl_up(inc, d, 64);
            if (tid >= d) inc += u;
        }
        const int excl = inc - tot;
#pragma unroll
        for (int j = 0; j < 8; ++j) offs[tid * 8 + j] = excl + v[j];
    }
    __syncthreads();
#pragma unroll
    for (int h = 0; h < 2; ++h) {
        int local = tid + h * 256;
        int node = node0 + local;
        if (node < N) {
            stv[node] = base + offs[local];
            deg[node] = cnt[local];
            dinv[node] = rsqrtf((float)(cnt[local] + 1));
        }
    }
    __syncthreads();
    for (int i = tid; i < n_b; i += 256) {  // offs doubles as cursor
        int pk = ebuf[base + i];
        int pos = atomicAdd(&offs[pk & 511], 1);
        adj[base + pos] = pk >> 9;
    }
}

// ---------------- MFMA GEMM: tp[i][:] = fp16( dinv[i] * (X[i][:] @ W) ), K=128
template <int BN, bool AFP16>
__launch_bounds__(256, 4)
__global__ void k_gemm_mfma(const void* __restrict__ Xv, const _Float16* __restrict__ wsz,
                            const float* __restrict__ dinv, __half* __restrict__ out, int N) {
    constexpr int NT = BN / 16;
    constexpr int PAD = 8;
    __shared__ __align__(16) _Float16 smem[BN * 128];  // B frags; reused for epilogue

    const int tid = threadIdx.x;
    for (int i = tid; i < BN * 16; i += 256)
        *(uint4*)&smem[i << 3] = *(const uint4*)&wsz[i << 3];

    const int w = tid >> 6;
    const int lane = tid & 63;
    const int q = lane >> 4;
    const int m = lane & 15;
    const int row0 = blockIdx.x * 64;
    const int arow = row0 + w * 16 + m;
    const int arowc = arow < N ? arow : N - 1;

    float4v acc[NT];
#pragma unroll
    for (int nt = 0; nt < NT; ++nt) acc[nt] = (float4v){0.f, 0.f, 0.f, 0.f};

    __syncthreads();

#pragma unroll
    for (int kblk = 0; kblk < 4; ++kblk) {
        half8 af;
        if constexpr (AFP16) {
            const _Float16* A = (const _Float16*)Xv + (size_t)arowc * 128 + (q << 3);
            af = *(const half8*)(A + kblk * 32);
        } else {
            const float* A = (const float*)Xv + (size_t)arowc * 128 + (q << 3);
            float4 a0 = *(const float4*)(A + kblk * 32);
            float4 a1 = *(const float4*)(A + kblk * 32 + 4);
            af[0] = (_Float16)a0.x; af[1] = (_Float16)a0.y;
            af[2] = (_Float16)a0.z; af[3] = (_Float16)a0.w;
            af[4] = (_Float16)a1.x; af[5] = (_Float16)a1.y;
            af[6] = (_Float16)a1.z; af[7] = (_Float16)a1.w;
        }
#pragma unroll
        for (int nt = 0; nt < NT; ++nt) {
            half8 bf = *(const half8*)&smem[(((nt << 2) + kblk) << 9) + (lane << 3)];
            acc[nt] = __builtin_amdgcn_mfma_f32_16x16x32_f16(af, bf, acc[nt], 0, 0, 0);
        }
    }

    float s[4];
#pragma unroll
    for (int r = 0; r < 4; ++r) {
        int rr = row0 + w * 16 + q * 4 + r;
        s[r] = dinv[rr < N ? rr : N - 1];
    }
    __syncthreads();  // all B reads done before smem reuse
    _Float16* eb = smem;
#pragma unroll
    for (int nt = 0; nt < NT; ++nt)
#pragma unroll
        for (int r = 0; r < 4; ++r)
            eb[(w * 16 + q * 4 + r) * (BN + PAD) + nt * 16 + m] = (_Float16)(acc[nt][r] * s[r]);
    __syncthreads();
    constexpr int CPR = BN / 8;
    for (int i = tid; i < 64 * CPR; i += 256) {
        int row = i / CPR;
        int cf = (i % CPR) * 8;
        if (row0 + row < N)
            *(uint4*)&out[(size_t)(row0 + row) * BN + cf] = *(uint4*)&eb[row * (BN + PAD) + cf];
    }
}

// ---------------- d=128 aggregation: TWO nodes per wave for 2x miss-level parallelism
// 4 groups of 16 lanes; group g handles edge e+g of each node; lane loads uint4 (8 cols).
template <bool RELU>
__launch_bounds__(256)
__global__ void k_agg128(const __half* __restrict__ tp, const int* __restrict__ adj,
                         const int* __restrict__ startv, const int* __restrict__ deg,
                         const float* __restrict__ dinv, const float* __restrict__ bias,
                         _Float16* __restrict__ out, int N) {
    const int n0 = (blockIdx.x << 3) + ((threadIdx.x >> 6) << 1);
    const int lane = threadIdx.x & 63;
    if (n0 >= N) return;
    const bool has1 = (n0 + 1) < N;
    const int n1 = has1 ? n0 + 1 : n0;
    const int s0 = startv[n0], s1 = startv[n1];
    const int c0 = deg[n0];
    const int c1 = has1 ? deg[n1] : 0;
    const float one = 1.0f;
    const int g = lane >> 4;        // edge group 0..3
    const int sl = lane & 15;       // 16 B chunk within row
    const uint4* rowb = (const uint4*)tp;   // row stride = 16 uint4 (256 B)

    float a0[8] = {0.f, 0.f, 0.f, 0.f, 0.f, 0.f, 0.f, 0.f};
    float a1[8] = {0.f, 0.f, 0.f, 0.f, 0.f, 0.f, 0.f, 0.f};
    auto addrow = [&](float* acc, uint4 v) {
        fmix_lo(acc[0], v.x, one); fmix_hi(acc[1], v.x, one);
        fmix_lo(acc[2], v.y, one); fmix_hi(acc[3], v.y, one);
        fmix_lo(acc[4], v.z, one); fmix_hi(acc[5], v.z, one);
        fmix_lo(acc[6], v.w, one); fmix_hi(acc[7], v.w, one);
    };

    // self-loops: both rows in flight together
    {
        uint4 r0 = rowb[(size_t)n0 * 16 + sl];
        uint4 r1 = rowb[(size_t)n1 * 16 + sl];
        if (g == 0) { addrow(a0, r0); if (has1) addrow(a1, r1); }
    }

    // joint main loop: 8 row-gathers in flight per lane
    int e = 0;
    const int mc = min(c0, c1);
    for (; e + 16 <= mc; e += 16) {
        int j0[4], j1[4];
#pragma unroll
        for (int u = 0; u < 4; ++u) { j0[u] = adj[s0 + e + 4 * u + g]; j1[u] = adj[s1 + e + 4 * u + g]; }
        uint4 v0[4], v1[4];
#pragma unroll
        for (int u = 0; u < 4; ++u) { v0[u] = rowb[(size_t)j0[u] * 16 + sl]; v1[u] = rowb[(size_t)j1[u] * 16 + sl]; }
#pragma unroll
        for (int u = 0; u < 4; ++u) { addrow(a0, v0[u]); addrow(a1, v1[u]); }
    }

    // per-node finish ladder (branches are wave-uniform)
    auto finish = [&](float* acc, int s, int cnt, int eS) {
        int ee = eS;
        for (; ee + 16 <= cnt; ee += 16) {
            int j[4];
#pragma unroll
            for (int u = 0; u < 4; ++u) j[u] = adj[s + ee + 4 * u + g];
            uint4 v[4];
#pragma unroll
            for (int u = 0; u < 4; ++u) v[u] = rowb[(size_t)j[u] * 16 + sl];
#pragma unroll
            for (int u = 0; u < 4; ++u) addrow(acc, v[u]);
        }
        if (ee + 8 <= cnt) {
            int j[2];
#pragma unroll
            for (int u = 0; u < 2; ++u) j[u] = adj[s + ee + 4 * u + g];
            uint4 v[2];
#pragma unroll
            for (int u = 0; u < 2; ++u) v[u] = rowb[(size_t)j[u] * 16 + sl];
#pragma unroll
            for (int u = 0; u < 2; ++u) addrow(acc, v[u]);
            ee += 8;
        }
        if (ee + 4 <= cnt) {
            addrow(acc, rowb[(size_t)adj[s + ee + g] * 16 + sl]);
            ee += 4;
        }
        if (ee + g < cnt)
            addrow(acc, rowb[(size_t)adj[s + ee + g] * 16 + sl]);
    };
    finish(a0, s0, c0, e);
    if (has1) finish(a1, s1, c1, e);

#pragma unroll
    for (int i = 0; i < 8; ++i) {
        a0[i] += __shfl_xor(a0[i], 32);
        a0[i] += __shfl_xor(a0[i], 16);
        a1[i] += __shfl_xor(a1[i], 32);
        a1[i] += __shfl_xor(a1[i], 16);
    }
    if (g == 0) {
        float4 b0 = *(const float4*)&bias[sl * 8];
        float4 b1 = *(const float4*)&bias[sl * 8 + 4];
        const float di0 = dinv[n0];
        float o[8];
        o[0] = di0 * a0[0] + b0.x; o[1] = di0 * a0[1] + b0.y;
        o[2] = di0 * a0[2] + b0.z; o[3] = di0 * a0[3] + b0.w;
        o[4] = di0 * a0[4] + b1.x; o[5] = di0 * a0[5] + b1.y;
        o[6] = di0 * a0[6] + b1.z; o[7] = di0 * a0[7] + b1.w;
        if (RELU)
#pragma unroll
            for (int i = 0; i < 8; ++i) o[i] = fmaxf(o[i], 0.f);
        __half2 ov[4];
#pragma unroll
        for (int i = 0; i < 4; ++i) ov[i] = __floats2half2_rn(o[2 * i], o[2 * i + 1]);
        *(uint4*)&out[(size_t)n0 * 128 + sl * 8] = *(uint4*)ov;
        if (has1) {
            const float di1 = dinv[n1];
            o[0] = di1 * a1[0] + b0.x; o[1] = di1 * a1[1] + b0.y;
            o[2] = di1 * a1[2] + b0.z; o[3] = di1 * a1[3] + b0.w;
            o[4] = di1 * a1[4] + b1.x; o[5] = di1 * a1[5] + b1.y;
            o[6] = di1 * a1[6] + b1.z; o[7] = di1 * a1[7] + b1.w;
            if (RELU)
#pragma unroll
                for (int i = 0; i < 8; ++i) o[i] = fmaxf(o[i], 0.f);
#pragma unroll
            for (int i = 0; i < 4; ++i) ov[i] = __floats2half2_rn(o[2 * i], o[2 * i + 1]);
            *(uint4*)&out[(size_t)n1 * 128 + sl * 8] = *(uint4*)ov;
        }
    }
}

// ---------------- d=64 aggregation (fp32 out): TWO nodes per wave
__launch_bounds__(256)
__global__ void k_agg64(const __half* __restrict__ tp, const int* __restrict__ adj,
                        const int* __restrict__ startv, const int* __restrict__ deg,
                        const float* __restrict__ dinv, const float* __restrict__ bias,
                        float* __restrict__ out, int N) {
    const int n0 = (blockIdx.x << 3) + ((threadIdx.x >> 6) << 1);
    const int lane = threadIdx.x & 63;
    if (n0 >= N) return;
    const bool has1 = (n0 + 1) < N;
    const int n1 = has1 ? n0 + 1 : n0;
    const int s0 = startv[n0], s1 = startv[n1];
    const int c0 = deg[n0];
    const int c1 = has1 ? deg[n1] : 0;
    const float one = 1.0f;
    const int g = lane >> 4;
    const int sl = lane & 15;
    const uint2* rowb = (const uint2*)tp;   // row stride = 16 uint2 (128 B)

    float a0[4] = {0.f, 0.f, 0.f, 0.f};
    float a1[4] = {0.f, 0.f, 0.f, 0.f};
    auto addrow = [&](float* acc, uint2 v) {
        fmix_lo(acc[0], v.x, one); fmix_hi(acc[1], v.x, one);
        fmix_lo(acc[2], v.y, one); fmix_hi(acc[3], v.y, one);
    };
    {
        uint2 r0 = rowb[(size_t)n0 * 16 + sl];
        uint2 r1 = rowb[(size_t)n1 * 16 + sl];
        if (g == 0) { addrow(a0, r0); if (has1) addrow(a1, r1); }
    }

    int e = 0;
    const int mc = min(c0, c1);
    for (; e + 16 <= mc; e += 16) {
        int j0[4], j1[4];
#pragma unroll
        for (int u = 0; u < 4; ++u) { j0[u] = adj[s0 + e + 4 * u + g]; j1[u] = adj[s1 + e + 4 * u + g]; }
        uint2 v0[4], v1[4];
#pragma unroll
        for (int u = 0; u < 4; ++u) { v0[u] = rowb[(size_t)j0[u] * 16 + sl]; v1[u] = rowb[(size_t)j1[u] * 16 + sl]; }
#pragma unroll
        for (int u = 0; u < 4; ++u) { addrow(a0, v0[u]); addrow(a1, v1[u]); }
    }

    auto finish = [&](float* acc, int s, int cnt, int eS) {
        int ee = eS;
        for (; ee + 16 <= cnt; ee += 16) {
            int j[4];
#pragma unroll
            for (int u = 0; u < 4; ++u) j[u] = adj[s + ee + 4 * u + g];
            uint2 v[4];
#pragma unroll
            for (int u = 0; u < 4; ++u) v[u] = rowb[(size_t)j[u] * 16 + sl];
#pragma unroll
            for (int u = 0; u < 4; ++u) addrow(acc, v[u]);
        }
        if (ee + 8 <= cnt) {
            int j[2];
#pragma unroll
            for (int u = 0; u < 2; ++u) j[u] = adj[s + ee + 4 * u + g];
            uint2 v[2];
#pragma unroll
            for (int u = 0; u < 2; ++u) v[u] = rowb[(size_t)j[u] * 16 + sl];
#pragma unroll
            for (int u = 0; u < 2; ++u) addrow(acc, v[u]);
            ee += 8;
        }
        if (ee + 4 <= cnt) {
            addrow(acc, rowb[(size_t)adj[s + ee + g] * 16 + sl]);
            ee += 4;
        }
        if (ee + g < cnt)
            addrow(acc, rowb[(size_t)adj[s + ee + g] * 16 + sl]);
    };
    finish(a0, s0, c0, e);
    if (has1) finish(a1, s1, c1, e);

#pragma unroll
    for (int i = 0; i < 4; ++i) {
        a0[i] += __shfl_xor(a0[i], 32);
        a0[i] += __shfl_xor(a0[i], 16);
        a1[i] += __shfl_xor(a1[i], 32);
        a1[i] += __shfl_xor(a1[i], 16);
    }
    if (g == 0) {
        float4 bb = *(const float4*)&bias[sl * 4];
        const float di0 = dinv[n0];
        float4 o;
        o.x = di0 * a0[0] + bb.x; o.y = di0 * a0[1] + bb.y;
        o.z = di0 * a0[2] + bb.z; o.w = di0 * a0[3] + bb.w;
        *(float4*)&out[(size_t)n0 * 64 + sl * 4] = o;
        if (has1) {
            const float di1 = dinv[n1];
            o.x = di1 * a1[0] + bb.x; o.y = di1 * a1[1] + bb.y;
            o.z = di1 * a1[2] + bb.z; o.w = di1 * a1[3] + bb.w;
            *(float4*)&out[(size_t)n1 * 64 + sl * 4] = o;
        }
    }
}

extern "C" void kernel_launch(void* const* d_in, const int* in_sizes, int n_in,
                              void* d_out, int out_size, void* d_ws, size_t ws_size,
                              hipStream_t stream) {
    const float* x  = (const float*)d_in[0];
    const int*   ei = (const int*)d_in[1];
    const float* W1 = (const float*)d_in[2];
    const float* b1 = (const float*)d_in[3];
    const float* W2 = (const float*)d_in[4];
    const float* b2 = (const float*)d_in[5];
    const float* W3 = (const float*)d_in[6];
    const float* b3 = (const float*)d_in[7];
    float* out = (float*)d_out;
    const int* src = ei;            // edge_index[0]
    const int* dst = ei + N_EDGES;  // edge_index[1]

    char* p = (char*)d_ws;
    __half* tp      = (__half*)p;    p += (size_t)N_NODES * 128 * 2;   // 25.6 MB
    _Float16* hbuf  = (_Float16*)p;  p += (size_t)N_NODES * 128 * 2;   // 25.6 MB
    int*   deg  = (int*)p;    p += (size_t)N_NODES * 4;
    float* dinv = (float*)p;  p += (size_t)N_NODES * 4;
    int*   stv  = (int*)p;    p += (size_t)N_NODES * 4;
    int*   bCur = (int*)p;    p += 1024;                               // bucket fill counts
    int*   adj  = (int*)p;    p += (size_t)NBUCKET * CAP * 4 + 16384;  // 7.0 MB bucketed
    _Float16* wz1 = (_Float16*)p; p += 16384 * 2;                      // 32 KB
    _Float16* wz2 = (_Float16*)p; p += 16384 * 2;                      // 32 KB
    _Float16* wz3 = (_Float16*)p; p += 8192 * 2;                       // 16 KB
    size_t need = (size_t)(p - (char*)d_ws);
    if (ws_size < need) return;  // visible failure rather than OOB

    int* ebuf = (int*)tp;  // 7.0 MB alias; tp not live until layer-1 GEMM

    hipMemsetAsync(bCur, 0, 1024, stream);
    k_part_wswz<<<276, 256, 0, stream>>>(src, dst, bCur, ebuf, N_EDGES,
                                         W1, W2, W3, wz1, wz2, wz3);
    k_bsort<<<NBUCKET, 256, 0, stream>>>(ebuf, bCur, adj, stv, deg, dinv, N_NODES);

    const int gb = (N_NODES + 63) / 64;
    const int ab = (N_NODES + 7) / 8;
    // layer 1: relu(agg(x@W1) + b1) -> fp16 hbuf
    k_gemm_mfma<128, false><<<gb, 256, 0, stream>>>(x, wz1, dinv, tp, N_NODES);
    k_agg128<true><<<ab, 256, 0, stream>>>(tp, adj, stv, deg, dinv, b1, hbuf, N_NODES);
    // layer 2
    k_gemm_mfma<128, true><<<gb, 256, 0, stream>>>(hbuf, wz2, dinv, tp, N_NODES);
    k_agg128<true><<<ab, 256, 0, stream>>>(tp, adj, stv, deg, dinv, b2, hbuf, N_NODES);
    // layer 3: agg(h@W3) + b3 (no relu) -> fp32 out
    k_gemm_mfma<64, true><<<gb, 256, 0, stream>>>(hbuf, wz3, dinv, tp, N_NODES);
    k_agg64<<<ab, 256, 0, stream>>>(tp, adj, stv, deg, dinv, b3, out, N_NODES);
}